// Round 9
// baseline (488.331 us; speedup 1.0000x reference)
//
#include <hip/hip_runtime.h>
#include <stdint.h>

typedef __attribute__((ext_vector_type(8))) short s16x8;
typedef __attribute__((ext_vector_type(4))) float f32x4;
typedef unsigned short u16;

#define DEV static __device__ __forceinline__

DEV f32x4 mfma16(s16x8 a, s16x8 b, f32x4 c) {
    return __builtin_amdgcn_mfma_f32_16x16x32_bf16(a, b, c, 0, 0, 0);
}

DEV void gld16(const void* g, void* l) {
    __builtin_amdgcn_global_load_lds(
        (const __attribute__((address_space(1))) void*)g,
        (__attribute__((address_space(3))) void*)l, 16, 0, 0);
}

DEV u16 f2bf(float x) {
    union { float f; unsigned u; } v; v.f = x;
    unsigned r = v.u + 0x7FFFu + ((v.u >> 16) & 1u);
    return (u16)(r >> 16);
}
DEV float bf2f(u16 h) { return __uint_as_float(((unsigned)h) << 16); }

#define SCHED0() __builtin_amdgcn_sched_barrier(0)
#define LGKM0() do { asm volatile("s_waitcnt lgkmcnt(0)" ::: "memory"); __builtin_amdgcn_sched_barrier(0); } while (0)

// ---------------- weight / input conversion ----------------
struct WPtrs { const float* p[16]; };

__global__ void k_conv_w(WPtrs wp, u16* wd, u16* wq) {
    int t = blockIdx.x * 256 + threadIdx.x;
    int mat = t >> 14;
    int e = (t & 16383) << 2;
    const float* s = wp.p[mat] + e;
    u16* d = (mat < 8 ? wd + mat * 65536 : wq + (mat - 8) * 65536) + e;
    float4 v = *(const float4*)s;
    d[0] = f2bf(v.x); d[1] = f2bf(v.y); d[2] = f2bf(v.z); d[3] = f2bf(v.w);
}

__global__ void k_conv_x(const float* dn, const float* qn, u16* xd, u16* xq) {
    int t = blockIdx.x * 256 + threadIdx.x;
    int h = t >> 19;
    int e = (t & 524287) << 2;
    const float* s = (h ? qn : dn) + e;
    u16* d = (h ? xq : xd) + e;
    float4 v = *(const float4*)s;
    d[0] = f2bf(v.x); d[1] = f2bf(v.y); d[2] = f2bf(v.z); d[3] = f2bf(v.w);
}

// ---------------- mask pre-pass: pack to bit-planes + nb rowsums ----------------
struct QuadCfg {
    const int* rm; const int* cm; int roff, coff, diag;
    unsigned* pl; unsigned* pr; unsigned char* dgp; float* nb;
};

__global__ __launch_bounds__(256) void k_mask(QuadCfg q0, QuadCfg q1, QuadCfg q2, QuadCfg q3,
        const int* ner, const int* graph) {
    const int z = blockIdx.z;
    const QuadCfg c = z == 0 ? q0 : z == 1 ? q1 : z == 2 ? q2 : q3;
    const int b = blockIdx.y;
    const int t = threadIdx.x;
    const int sub = t >> 5, w = t & 31;
    const int i = blockIdx.x * 8 + sub;
    const int rm = c.rm[b * 1024 + i] != 0;
    size_t rowbase = ((size_t)(b * 2048 + c.roff + i)) * 2048 + c.coff + w * 32;
    const int4* np = (const int4*)(ner + rowbase);
    const int4* gp = (const int4*)(graph + rowbase);
    const int4* cp = (const int4*)(c.cm + b * 1024 + w * 32);
    unsigned v = 0, gw = 0;
#pragma unroll
    for (int k = 0; k < 8; ++k) {
        int4 nv = np[k], gv = gp[k], cv = cp[k];
        unsigned bs = k * 4;
        v  |= ((unsigned)(rm & (cv.x != 0) & (nv.x != 0))) << bs;
        v  |= ((unsigned)(rm & (cv.y != 0) & (nv.y != 0))) << (bs + 1);
        v  |= ((unsigned)(rm & (cv.z != 0) & (nv.z != 0))) << (bs + 2);
        v  |= ((unsigned)(rm & (cv.w != 0) & (nv.w != 0))) << (bs + 3);
        gw |= ((unsigned)(gv.x != 0)) << bs;
        gw |= ((unsigned)(gv.y != 0)) << (bs + 1);
        gw |= ((unsigned)(gv.z != 0)) << (bs + 2);
        gw |= ((unsigned)(gv.w != 0)) << (bs + 3);
    }
    unsigned e = v;
    if (c.diag && (i >> 5) == w) {
        e &= ~(1u << (i & 31));
        c.dgp[b * 1024 + i] = (unsigned char)((v >> (i & 31)) & 1u);
    }
    unsigned lb = e & gw, rb = e & ~gw;
    size_t widx = ((size_t)(b * 1024 + i)) * 32 + w;
    c.pl[widx] = lb;
    c.pr[widx] = rb;
    int cnt = __popc(e);
    cnt += __shfl_xor(cnt, 1); cnt += __shfl_xor(cnt, 2);
    cnt += __shfl_xor(cnt, 4); cnt += __shfl_xor(cnt, 8); cnt += __shfl_xor(cnt, 16);
    if (w == 0) atomicAdd(c.nb + b * 1024 + i, (float)cnt);
}

// ---------------- projection GEMM: out = X @ W^T ----------------
__global__ __launch_bounds__(256, 1) void k_proj(const u16* xd, const u16* xq,
        const u16* wdm, const u16* wqm, u16* tokd, u16* tokq, u16* vtd, u16* vtq) {
    __shared__ __align__(16) char smem[16384];
    char* As = smem; char* Bs = smem + 8192;
    const int lane = threadIdx.x & 63, wid = threadIdx.x >> 6;
    const int z = blockIdx.z, grp = z >> 3, w = z & 7;
    const u16* X = grp ? xq : xd;
    const u16* W = (grp ? wqm : wdm) + w * 65536;
    const int m0 = blockIdx.x * 128, n0 = blockIdx.y * 128;
    const int wr = wid >> 1, wc = wid & 1;
    const int rl = lane & 15, g = lane >> 4;
    const f32x4 fz = {0.f, 0.f, 0.f, 0.f};
    f32x4 acc[4][4];
#pragma unroll
    for (int i = 0; i < 4; ++i)
#pragma unroll
        for (int j = 0; j < 4; ++j) acc[i][j] = fz;

    for (int kt = 0; kt < 8; ++kt) {
#pragma unroll
        for (int t = 0; t < 2; ++t) {
            int iid = wid * 2 + t;
            int ldso = iid * 1024 + lane * 16;
            int row = ldso >> 6, inrow = ldso & 63;
            int src = inrow ^ ((row & 3) << 4);
            gld16((const char*)X + ((size_t)(m0 + row) * 512 + kt * 64 + src), As + iid * 1024);
            gld16((const char*)W + ((size_t)(n0 + row) * 512 + kt * 64 + src), Bs + iid * 1024);
        }
        __syncthreads();
        s16x8 av[4], bv[4];
#pragma unroll
        for (int rf = 0; rf < 4; ++rf) {
            int row = wr * 64 + rf * 16 + rl;
            av[rf] = *(const s16x8*)(As + row * 64 + ((g * 16) ^ ((row & 3) << 4)));
        }
#pragma unroll
        for (int cf = 0; cf < 4; ++cf) {
            int row = wc * 64 + cf * 16 + rl;
            bv[cf] = *(const s16x8*)(Bs + row * 64 + ((g * 16) ^ ((row & 3) << 4)));
        }
#pragma unroll
        for (int rf = 0; rf < 4; ++rf)
#pragma unroll
            for (int cf = 0; cf < 4; ++cf)
                acc[rf][cf] = mfma16(av[rf], bv[cf], acc[rf][cf]);
        __syncthreads();
    }
    if (w < 4) {
        u16* out = (grp ? tokq : tokd) + (size_t)w * 2097152;
#pragma unroll
        for (int rf = 0; rf < 4; ++rf)
#pragma unroll
            for (int cf = 0; cf < 4; ++cf) {
                int n = n0 + wc * 64 + cf * 16 + rl;
                int m = m0 + wr * 64 + rf * 16 + g * 4;
#pragma unroll
                for (int r = 0; r < 4; ++r)
                    out[(size_t)(m + r) * 256 + n] = f2bf(acc[rf][cf][r]);
            }
    } else {
        u16* out = (grp ? vtq : vtd) + (size_t)(w - 4) * 2097152;
#pragma unroll
        for (int rf = 0; rf < 4; ++rf)
#pragma unroll
            for (int cf = 0; cf < 4; ++cf) {
                int n = n0 + wc * 64 + cf * 16 + rl;
                int m = m0 + wr * 64 + rf * 16 + g * 4;
                int b = m >> 10, tok = m & 1023;
                unsigned lo = (unsigned)f2bf(acc[rf][cf][0]) | ((unsigned)f2bf(acc[rf][cf][1]) << 16);
                unsigned hi = (unsigned)f2bf(acc[rf][cf][2]) | ((unsigned)f2bf(acc[rf][cf][3]) << 16);
                uint2 u; u.x = lo; u.y = hi;
                *(uint2*)(out + ((size_t)(b * 256 + n)) * 1024 + tok) = u;
            }
    }
}

// ---------------- fused masked attention (one quadrant per z) ----------------
struct PhaseCfg {
    const u16* Q; const u16* K; const u16* Vl; const u16* Vr;
    const unsigned* pl; const unsigned* pr; const unsigned char* dgp;
    float scale; float* po;
};

// BARRIER-FREE LOOP. Block = 2 waves over the SAME 16 rows; wave w owns
// j-half [w*512, w*512+512), 16 j-tiles of 32, fully independent:
//   - private K LDS tile (own gld16 stage, counted vmcnt -- no cross-wave WAR)
//   - private P bounce buffer (same-wave write -> lgkmcnt(0) -> read, NO barrier)
//   - full-row softmax in-wave; V direct from L2 (all 256 ch, 2 halves)
// End merge: (m,den) exchange + acc rescale-add via LDS, 2 syncthreads total.
// LDS 38144B: Ks[w]@w*16384 (16K each); Pl[w]@32768+w*2560, Pr +1280;
//   mS@37888 (128B), dS@38016 (128B). accS reuses smem@0 after loop.
__global__ __launch_bounds__(128, 2) void k_attn(PhaseCfg c0, PhaseCfg c1,
        PhaseCfg c2, PhaseCfg c3) {
    // bijective XCD swizzle: each XCD gets 4 (b,z) pairs x 64 i-blocks
    const int lin = blockIdx.x + 64 * blockIdx.y + 512 * blockIdx.z;
    const int xcd = lin & 7, rest = lin >> 3;
    const int pair = xcd * 4 + (rest >> 6);
    const int i0 = (rest & 63) * 16;
    const int z = pair >> 3, b = pair & 7;
    const PhaseCfg c = z == 0 ? c0 : z == 1 ? c1 : z == 2 ? c2 : c3;
    const int lane = threadIdx.x & 63, w = threadIdx.x >> 6;   // 2 waves
    const int rl = lane & 15, g = lane >> 4;

    __shared__ __align__(16) char smem[38144];
    char* Ks = smem + w * 16384;
    u16* Pl = (u16*)(smem + 32768 + w * 2560);
    u16* Pr = (u16*)(smem + 32768 + w * 2560 + 1280);
    float* mS = (float*)(smem + 37888);
    float* dS = (float*)(smem + 38016);

    const char* Kg  = (const char*)c.K  + (size_t)b * 524288;
    const char* Vlg = (const char*)c.Vl + (size_t)b * 524288;
    const char* Vrg = (const char*)c.Vr + (size_t)b * 524288;

    // Q fragments: rows i0+rl (A-frag: lane holds row rl, k = kk*32 + g*8)
    s16x8 qf[8];
    {
        const u16* Qb = c.Q + (size_t)(b * 1024 + i0 + rl) * 256 + g * 8;
#pragma unroll
        for (int kf = 0; kf < 8; ++kf) qf[kf] = *(const s16x8*)(Qb + kf * 32);
    }
    const int iqb = i0 + g * 4;
    const unsigned* lpRow = c.pl + ((size_t)(b << 10) + iqb) * 32;
    const unsigned* rpRow = c.pr + ((size_t)(b << 10) + iqb) * 32;

    unsigned dgv[4];
#pragma unroll
    for (int r = 0; r < 4; ++r)
        dgv[r] = c.dgp ? (unsigned)c.dgp[b * 1024 + iqb + r] : 0u;

    // stage own 16KB K tile (32 j-rows x 512B), 16 gld16, swz ^((row&7)<<4)
    auto STAGE_K = [&](int jt) {
#pragma unroll
        for (int t = 0; t < 16; ++t) {
            int ldso = t * 1024 + lane * 16;
            int row = ldso >> 9, inrow = ldso & 511;
            int src = inrow ^ ((row & 7) << 4);
            gld16(Kg + ((size_t)(w * 512 + jt * 32 + row)) * 512 + src, Ks + t * 1024);
        }
    };
    unsigned lw[4], rw[4];
    auto MLOAD = [&](int jt) {
#pragma unroll
        for (int r = 0; r < 4; ++r) {
            lw[r] = lpRow[r * 32 + w * 16 + jt];
            rw[r] = rpRow[r * 32 + w * 16 + jt];
        }
    };

    STAGE_K(0);
    MLOAD(0);

    const f32x4 fz = {0.f, 0.f, 0.f, 0.f};
    f32x4 acc[16];
#pragma unroll
    for (int j = 0; j < 16; ++j) acc[j] = fz;
    float mrow[4] = {-1e30f, -1e30f, -1e30f, -1e30f};
    float dden[4] = {0.f, 0.f, 0.f, 0.f};

#pragma unroll 1
    for (int jt = 0; jt < 16; ++jt) {
        const int j0g = w * 512 + jt * 32;

        // V half-0 issued at top: latency covered by QK+softmax
        s16x8 vl[8], vr[8];
#pragma unroll
        for (int cf = 0; cf < 8; ++cf) {
            size_t off = (size_t)(cf * 16 + rl) * 2048 + (size_t)(j0g + g * 8) * 2;
            vl[cf] = *(const s16x8*)(Vlg + off);
            vr[cf] = *(const s16x8*)(Vrg + off);
        }
        // outstanding: STAGE(jt)=16 (oldest), MLOAD(jt)=8, Vh0=16 -> drain stage
        asm volatile("s_waitcnt vmcnt(24)" ::: "memory");
        SCHED0();

        // S = Q K^T : 16 rows x 32 cols, in-wave
        f32x4 s0 = fz, s1 = fz;
#pragma unroll
        for (int kk = 0; kk < 8; ++kk) {
            int jr0 = rl, jr1 = 16 + rl;
            s16x8 b0 = *(const s16x8*)(Ks + jr0 * 512 + ((kk * 64 + g * 16) ^ ((jr0 & 7) << 4)));
            s16x8 b1 = *(const s16x8*)(Ks + jr1 * 512 + ((kk * 64 + g * 16) ^ ((jr1 & 7) << 4)));
            s0 = mfma16(qf[kk], b0, s0);
            s1 = mfma16(qf[kk], b1, s1);
        }

        // masks from bits; frag: row = iqb+r, cols j0g+rl / j0g+16+rl
        float sv0[4], sv1[4];
        int l0[4], l1[4], r0m[4], r1m[4];
#pragma unroll
        for (int r = 0; r < 4; ++r) {
            unsigned vw = lw[r] | rw[r];
            int row = iqb + r;
            if ((w * 16 + jt) == (row >> 5)) vw |= dgv[r] << (row & 31);
            int v0 = (vw >> rl) & 1;
            int v1 = (vw >> (16 + rl)) & 1;
            sv0[r] = v0 ? s0[r] * c.scale : -1e30f;
            sv1[r] = v1 ? s1[r] * c.scale : -1e30f;
            l0[r] = (lw[r] >> rl) & 1;        r0m[r] = (rw[r] >> rl) & 1;
            l1[r] = (lw[r] >> (16 + rl)) & 1; r1m[r] = (rw[r] >> (16 + rl)) & 1;
        }
        // online softmax, full row in-wave
        float rsv[4];
#pragma unroll
        for (int r = 0; r < 4; ++r) {
            float t = fmaxf(sv0[r], sv1[r]);
            t = fmaxf(t, __shfl_xor(t, 1));
            t = fmaxf(t, __shfl_xor(t, 2));
            t = fmaxf(t, __shfl_xor(t, 4));
            t = fmaxf(t, __shfl_xor(t, 8));
            float mn = fmaxf(mrow[r], t);
            rsv[r] = __expf(mrow[r] - mn);
            mrow[r] = mn;
            float e0 = __expf(sv0[r] - mn);
            float e1 = __expf(sv1[r] - mn);
            dden[r] = dden[r] * rsv[r] + e0 + e1;
            int prow = g * 4 + r;
            Pl[prow * 40 + rl]      = l0[r]  ? f2bf(e0) : (u16)0;
            Pl[prow * 40 + 16 + rl] = l1[r]  ? f2bf(e1) : (u16)0;
            Pr[prow * 40 + rl]      = r0m[r] ? f2bf(e0) : (u16)0;
            Pr[prow * 40 + 16 + rl] = r1m[r] ? f2bf(e1) : (u16)0;
        }

        // prefetch next tile: K reads retired (MFMAs consumed), WAR-safe
        LGKM0();
        if (jt < 15) { STAGE_K(jt + 1); MLOAD(jt + 1); }

        // private P bounce: same-wave, lgkm only, NO barrier
        LGKM0();
        s16x8 pa = *(const s16x8*)((char*)Pl + rl * 80 + g * 16);
        s16x8 pb = *(const s16x8*)((char*)Pr + rl * 80 + g * 16);

        // rescale acc, then PV in 2 channel-halves
        f32x4 rsq = {rsv[0], rsv[1], rsv[2], rsv[3]};
#pragma unroll
        for (int j = 0; j < 16; ++j) acc[j] *= rsq;
#pragma unroll
        for (int cf = 0; cf < 8; ++cf)
            acc[cf] = mfma16(pb, vr[cf], mfma16(pa, vl[cf], acc[cf]));
        // V half-1 (latency partially covered by PV half-0)
#pragma unroll
        for (int cf = 0; cf < 8; ++cf) {
            size_t off = (size_t)(128 + cf * 16 + rl) * 2048 + (size_t)(j0g + g * 8) * 2;
            vl[cf] = *(const s16x8*)(Vlg + off);
            vr[cf] = *(const s16x8*)(Vrg + off);
        }
#pragma unroll
        for (int cf = 0; cf < 8; ++cf)
            acc[8 + cf] = mfma16(pb, vr[cf], mfma16(pa, vl[cf], acc[8 + cf]));
    }

    // ---- merge the two j-halves ----
#pragma unroll
    for (int r = 0; r < 4; ++r) {
        float d = dden[r];
        d += __shfl_xor(d, 1); d += __shfl_xor(d, 2); d += __shfl_xor(d, 4); d += __shfl_xor(d, 8);
        dden[r] = d;
    }
    if (rl == 0) {
        f32x4 mv = {mrow[0], mrow[1], mrow[2], mrow[3]};
        f32x4 dv = {dden[0], dden[1], dden[2], dden[3]};
        *(f32x4*)(mS + w * 16 + g * 4) = mv;
        *(f32x4*)(dS + w * 16 + g * 4) = dv;
    }
    __syncthreads();
    f32x4 mo = *(const f32x4*)(mS + (w ^ 1) * 16 + g * 4);
    f32x4 dd2 = *(const f32x4*)(dS + (w ^ 1) * 16 + g * 4);
    float inv[4], sc[4];
#pragma unroll
    for (int r = 0; r < 4; ++r) {
        float M = fmaxf(mrow[r], mo[r]);
        sc[r] = __expf(mrow[r] - M);
        float dt = dden[r] * sc[r] + dd2[r] * __expf(mo[r] - M);
        inv[r] = dt > 0.f ? 1.f / dt : 0.f;
    }
    f32x4 scv = {sc[0], sc[1], sc[2], sc[3]};
#pragma unroll
    for (int j = 0; j < 16; ++j) acc[j] *= scv;

    float* accS = (float*)smem;   // 16KB, reuses K area (loop done)
    if (w == 1) {
#pragma unroll
        for (int j = 0; j < 16; ++j)
#pragma unroll
            for (int r = 0; r < 4; ++r)
                accS[(g * 4 + r) * 256 + j * 16 + rl] = acc[j][r];
    }
    __syncthreads();
    if (w == 0) {
#pragma unroll
        for (int j = 0; j < 16; ++j)
#pragma unroll
            for (int r = 0; r < 4; ++r) {
                int row = i0 + g * 4 + r;
                float v = (acc[j][r] + accS[(g * 4 + r) * 256 + j * 16 + rl]) * inv[r];
                c.po[(size_t)(b * 1024 + row) * 256 + j * 16 + rl] = v;
            }
    }
}

// ---------------- combine: out = relu(self + bias + (pA+pB)/max(nb,1)) ----------------
struct FinCfg {
    const float* pA; const float* pB; const float* nb;
    const u16* self; float* out;
};

__global__ __launch_bounds__(256) void k_fin(FinCfg f0, FinCfg f1, const float* bias) {
    const FinCfg f = blockIdx.y ? f1 : f0;
    int row = blockIdx.x * 4 + (threadIdx.x >> 6);
    int ch = (threadIdx.x & 63) * 4;
    size_t oi = (size_t)row * 256 + ch;
    float inv = 1.f / fmaxf(f.nb[row], 1.f);
    f32x4 a = *(const f32x4*)(f.pA + oi);
    f32x4 p = *(const f32x4*)(f.pB + oi);
    f32x4 bi = *(const f32x4*)(bias + ch);
    uint2 sv = *(const uint2*)(f.self + oi);
    float s[4] = { bf2f((u16)(sv.x & 0xffff)), bf2f((u16)(sv.x >> 16)),
                   bf2f((u16)(sv.y & 0xffff)), bf2f((u16)(sv.y >> 16)) };
    f32x4 o;
#pragma unroll
    for (int k = 0; k < 4; ++k)
        o[k] = fmaxf(s[k] + bi[k] + (a[k] + p[k]) * inv, 0.f);
    *(f32x4*)(f.out + oi) = o;
}

// ---------------- host ----------------
extern "C" void kernel_launch(void* const* d_in, const int* in_sizes, int n_in,
                              void* d_out, int out_size, void* d_ws, size_t ws_size,
                              hipStream_t stream) {
    (void)in_sizes; (void)n_in; (void)out_size; (void)ws_size;
    const float* d_node = (const float*)d_in[0];
    const float* q_node = (const float*)d_in[1];
    const float* b_self = (const float*)d_in[9];
    const int* dm = (const int*)d_in[18];
    const int* qm = (const int*)d_in[19];
    const int* ner = (const int*)d_in[20];
    const int* graph = (const int*)d_in[21];

    char* ws = (char*)d_ws;
    const size_t MB = 1024 * 1024;
    u16* xd   = (u16*)(ws + 0 * MB);
    u16* xq   = (u16*)(ws + 4 * MB);
    u16* wdm  = (u16*)(ws + 8 * MB);
    u16* wqm  = (u16*)(ws + 9 * MB);
    u16* tokd = (u16*)(ws + 10 * MB);     // [Qd, Kd, Kqd, SelfD]
    u16* tokq = (u16*)(ws + 26 * MB);     // [Qq, Kq, Kdq, SelfQ]
    u16* vtd  = (u16*)(ws + 42 * MB);     // [ddl, ddr, qdl, qdr] channel-major
    u16* vtq  = (u16*)(ws + 58 * MB);     // [qql, qqr, dql, dqr]
    float* nb_d = (float*)(ws + 74 * MB);
    float* nb_q = (float*)(ws + 74 * MB + 32768);
    unsigned char* dgd = (unsigned char*)(ws + 74 * MB + 65536);
    unsigned char* dgq = (unsigned char*)(ws + 74 * MB + 73728);
    float* Pdq  = (float*)(ws + 75 * MB);
    float* Pqd  = (float*)(ws + 83 * MB);
    unsigned* pl_dd = (unsigned*)(ws + 91 * MB);
    unsigned* pl_qq = (unsigned*)(ws + 92 * MB);
    unsigned* pl_dq = (unsigned*)(ws + 93 * MB);
    unsigned* pl_qd = (unsigned*)(ws + 94 * MB);
    unsigned* pr_dd = (unsigned*)(ws + 95 * MB);
    unsigned* pr_qq = (unsigned*)(ws + 96 * MB);
    unsigned* pr_dq = (unsigned*)(ws + 97 * MB);
    unsigned* pr_qd = (unsigned*)(ws + 98 * MB);

    float* outd = (float*)d_out;
    float* outq = outd + 2097152;

    WPtrs wp;
    wp.p[0]  = (const float*)d_in[2];   // W_dq_query -> Qd
    wp.p[1]  = (const float*)d_in[3];   // W_dk_key   -> Kd
    wp.p[2]  = (const float*)d_in[7];   // W_qd_fc    -> Kqd
    wp.p[3]  = (const float*)d_in[8];   // W_self     -> SelfD
    wp.p[4]  = (const float*)d_in[10];  // W_dd_l
    wp.p[5]  = (const float*)d_in[14];  // W_dd_r
    wp.p[6]  = (const float*)d_in[13];  // W_qd_l
    wp.p[7]  = (const float*)d_in[17];  // W_qd_r
    wp.p[8]  = (const float*)d_in[4];   // W_qq_query -> Qq
    wp.p[9]  = (const float*)d_in[5];   // W_qk_key   -> Kq
    wp.p[10] = (const float*)d_in[6];   // W_dq_fc    -> Kdq
    wp.p[11] = (const float*)d_in[8];   // W_self     -> SelfQ
    wp.p[12] = (const float*)d_in[11];  // W_qq_l
    wp.p[13] = (const float*)d_in[15];  // W_qq_r
    wp.p[14] = (const float*)d_in[12];  // W_dq_l
    wp.p[15] = (const float*)d_in[16];  // W_dq_r

    (void)hipMemsetAsync(ws + 74 * MB, 0, 65536, stream);   // nb_d + nb_q

    k_conv_w<<<1024, 256, 0, stream>>>(wp, wdm, wqm);
    k_conv_x<<<4096, 256, 0, stream>>>(d_node, q_node, xd, xq);

    QuadCfg mdd = { dm, dm, 0, 0, 1, pl_dd, pr_dd, dgd, nb_d };
    QuadCfg mqq = { qm, qm, 1024, 1024, 1, pl_qq, pr_qq, dgq, nb_q };
    QuadCfg mdq = { dm, qm, 0, 1024, 0, pl_dq, pr_dq, nullptr, nb_d };
    QuadCfg mqd = { qm, dm, 1024, 0, 0, pl_qd, pr_qd, nullptr, nb_q };
    k_mask<<<dim3(128, 8, 4), 256, 0, stream>>>(mdd, mqq, mdq, mqd, ner, graph);

    k_proj<<<dim3(64, 2, 16), 256, 0, stream>>>(xd, xq, wdm, wqm, tokd, tokq, vtd, vtq);

    const size_t M2 = 2097152;
    PhaseCfg dd = { tokd,          tokd + M2,     vtd,          vtd + M2,
                    pl_dd, pr_dd, dgd, 0.0625f, outd };
    PhaseCfg qq = { tokq,          tokq + M2,     vtq,          vtq + M2,
                    pl_qq, pr_qq, dgq, 0.0625f, outq };
    PhaseCfg dq = { xd,            tokq + 2 * M2, vtq + 2 * M2, vtq + 3 * M2,
                    pl_dq, pr_dq, nullptr, 1.0f, Pdq };
    PhaseCfg qd = { xq,            tokd + 2 * M2, vtd + 2 * M2, vtd + 3 * M2,
                    pl_qd, pr_qd, nullptr, 1.0f, Pqd };
    k_attn<<<dim3(64, 8, 4), 128, 0, stream>>>(dd, qq, dq, qd);

    FinCfg fd = { outd, Pdq, nb_d, tokd + 3 * M2, outd };
    FinCfg fq = { outq, Pqd, nb_q, tokq + 3 * M2, outq };
    k_fin<<<dim3(2048, 2), 256, 0, stream>>>(fd, fq, b_self);
}

// Round 10
// 441.835 us; speedup vs baseline: 1.1052x; 1.1052x over previous
//
#include <hip/hip_runtime.h>
#include <stdint.h>

typedef __attribute__((ext_vector_type(8))) short s16x8;
typedef __attribute__((ext_vector_type(4))) float f32x4;
typedef unsigned short u16;

#define DEV static __device__ __forceinline__

DEV f32x4 mfma16(s16x8 a, s16x8 b, f32x4 c) {
    return __builtin_amdgcn_mfma_f32_16x16x32_bf16(a, b, c, 0, 0, 0);
}

DEV void gld16(const void* g, void* l) {
    __builtin_amdgcn_global_load_lds(
        (const __attribute__((address_space(1))) void*)g,
        (__attribute__((address_space(3))) void*)l, 16, 0, 0);
}

DEV u16 f2bf(float x) {
    union { float f; unsigned u; } v; v.f = x;
    unsigned r = v.u + 0x7FFFu + ((v.u >> 16) & 1u);
    return (u16)(r >> 16);
}
DEV float bf2f(u16 h) { return __uint_as_float(((unsigned)h) << 16); }

#define SBAR() do { __builtin_amdgcn_sched_barrier(0); __builtin_amdgcn_s_barrier(); __builtin_amdgcn_sched_barrier(0); } while (0)
#define LGKM0() do { asm volatile("s_waitcnt lgkmcnt(0)" ::: "memory"); __builtin_amdgcn_sched_barrier(0); } while (0)

// ---------------- weight / input conversion ----------------
struct WPtrs { const float* p[16]; };

__global__ void k_conv_w(WPtrs wp, u16* wd, u16* wq) {
    int t = blockIdx.x * 256 + threadIdx.x;
    int mat = t >> 14;
    int e = (t & 16383) << 2;
    const float* s = wp.p[mat] + e;
    u16* d = (mat < 8 ? wd + mat * 65536 : wq + (mat - 8) * 65536) + e;
    float4 v = *(const float4*)s;
    d[0] = f2bf(v.x); d[1] = f2bf(v.y); d[2] = f2bf(v.z); d[3] = f2bf(v.w);
}

__global__ void k_conv_x(const float* dn, const float* qn, u16* xd, u16* xq) {
    int t = blockIdx.x * 256 + threadIdx.x;
    int h = t >> 19;
    int e = (t & 524287) << 2;
    const float* s = (h ? qn : dn) + e;
    u16* d = (h ? xq : xd) + e;
    float4 v = *(const float4*)s;
    d[0] = f2bf(v.x); d[1] = f2bf(v.y); d[2] = f2bf(v.z); d[3] = f2bf(v.w);
}

// ---------------- mask pre-pass: pack to bit-planes + nb rowsums ----------------
struct QuadCfg {
    const int* rm; const int* cm; int roff, coff, diag;
    unsigned* pl; unsigned* pr; unsigned char* dgp; float* nb;
};

__global__ __launch_bounds__(256) void k_mask(QuadCfg q0, QuadCfg q1, QuadCfg q2, QuadCfg q3,
        const int* ner, const int* graph) {
    const int z = blockIdx.z;
    const QuadCfg c = z == 0 ? q0 : z == 1 ? q1 : z == 2 ? q2 : q3;
    const int b = blockIdx.y;
    const int t = threadIdx.x;
    const int sub = t >> 5, w = t & 31;
    const int i = blockIdx.x * 8 + sub;
    const int rm = c.rm[b * 1024 + i] != 0;
    size_t rowbase = ((size_t)(b * 2048 + c.roff + i)) * 2048 + c.coff + w * 32;
    const int4* np = (const int4*)(ner + rowbase);
    const int4* gp = (const int4*)(graph + rowbase);
    const int4* cp = (const int4*)(c.cm + b * 1024 + w * 32);
    unsigned v = 0, gw = 0;
#pragma unroll
    for (int k = 0; k < 8; ++k) {
        int4 nv = np[k], gv = gp[k], cv = cp[k];
        unsigned bs = k * 4;
        v  |= ((unsigned)(rm & (cv.x != 0) & (nv.x != 0))) << bs;
        v  |= ((unsigned)(rm & (cv.y != 0) & (nv.y != 0))) << (bs + 1);
        v  |= ((unsigned)(rm & (cv.z != 0) & (nv.z != 0))) << (bs + 2);
        v  |= ((unsigned)(rm & (cv.w != 0) & (nv.w != 0))) << (bs + 3);
        gw |= ((unsigned)(gv.x != 0)) << bs;
        gw |= ((unsigned)(gv.y != 0)) << (bs + 1);
        gw |= ((unsigned)(gv.z != 0)) << (bs + 2);
        gw |= ((unsigned)(gv.w != 0)) << (bs + 3);
    }
    unsigned e = v;
    if (c.diag && (i >> 5) == w) {
        e &= ~(1u << (i & 31));
        c.dgp[b * 1024 + i] = (unsigned char)((v >> (i & 31)) & 1u);
    }
    unsigned lb = e & gw, rb = e & ~gw;
    size_t widx = ((size_t)(b * 1024 + i)) * 32 + w;
    c.pl[widx] = lb;
    c.pr[widx] = rb;
    int cnt = __popc(e);
    cnt += __shfl_xor(cnt, 1); cnt += __shfl_xor(cnt, 2);
    cnt += __shfl_xor(cnt, 4); cnt += __shfl_xor(cnt, 8); cnt += __shfl_xor(cnt, 16);
    if (w == 0) atomicAdd(c.nb + b * 1024 + i, (float)cnt);
}

// ---------------- projection GEMM: out = X @ W^T ----------------
__global__ __launch_bounds__(256, 1) void k_proj(const u16* xd, const u16* xq,
        const u16* wdm, const u16* wqm, u16* tokd, u16* tokq, u16* vtd, u16* vtq) {
    __shared__ __align__(16) char smem[16384];
    char* As = smem; char* Bs = smem + 8192;
    const int lane = threadIdx.x & 63, wid = threadIdx.x >> 6;
    const int z = blockIdx.z, grp = z >> 3, w = z & 7;
    const u16* X = grp ? xq : xd;
    const u16* W = (grp ? wqm : wdm) + w * 65536;
    const int m0 = blockIdx.x * 128, n0 = blockIdx.y * 128;
    const int wr = wid >> 1, wc = wid & 1;
    const int rl = lane & 15, g = lane >> 4;
    const f32x4 fz = {0.f, 0.f, 0.f, 0.f};
    f32x4 acc[4][4];
#pragma unroll
    for (int i = 0; i < 4; ++i)
#pragma unroll
        for (int j = 0; j < 4; ++j) acc[i][j] = fz;

    for (int kt = 0; kt < 8; ++kt) {
#pragma unroll
        for (int t = 0; t < 2; ++t) {
            int iid = wid * 2 + t;
            int ldso = iid * 1024 + lane * 16;
            int row = ldso >> 6, inrow = ldso & 63;
            int src = inrow ^ ((row & 3) << 4);
            gld16((const char*)X + ((size_t)(m0 + row) * 512 + kt * 64 + src), As + iid * 1024);
            gld16((const char*)W + ((size_t)(n0 + row) * 512 + kt * 64 + src), Bs + iid * 1024);
        }
        __syncthreads();
        s16x8 av[4], bv[4];
#pragma unroll
        for (int rf = 0; rf < 4; ++rf) {
            int row = wr * 64 + rf * 16 + rl;
            av[rf] = *(const s16x8*)(As + row * 64 + ((g * 16) ^ ((row & 3) << 4)));
        }
#pragma unroll
        for (int cf = 0; cf < 4; ++cf) {
            int row = wc * 64 + cf * 16 + rl;
            bv[cf] = *(const s16x8*)(Bs + row * 64 + ((g * 16) ^ ((row & 3) << 4)));
        }
#pragma unroll
        for (int rf = 0; rf < 4; ++rf)
#pragma unroll
            for (int cf = 0; cf < 4; ++cf)
                acc[rf][cf] = mfma16(av[rf], bv[cf], acc[rf][cf]);
        __syncthreads();
    }
    if (w < 4) {
        u16* out = (grp ? tokq : tokd) + (size_t)w * 2097152;
#pragma unroll
        for (int rf = 0; rf < 4; ++rf)
#pragma unroll
            for (int cf = 0; cf < 4; ++cf) {
                int n = n0 + wc * 64 + cf * 16 + rl;
                int m = m0 + wr * 64 + rf * 16 + g * 4;
#pragma unroll
                for (int r = 0; r < 4; ++r)
                    out[(size_t)(m + r) * 256 + n] = f2bf(acc[rf][cf][r]);
            }
    } else {
        u16* out = (grp ? vtq : vtd) + (size_t)(w - 4) * 2097152;
#pragma unroll
        for (int rf = 0; rf < 4; ++rf)
#pragma unroll
            for (int cf = 0; cf < 4; ++cf) {
                int n = n0 + wc * 64 + cf * 16 + rl;
                int m = m0 + wr * 64 + rf * 16 + g * 4;
                int b = m >> 10, tok = m & 1023;
                unsigned lo = (unsigned)f2bf(acc[rf][cf][0]) | ((unsigned)f2bf(acc[rf][cf][1]) << 16);
                unsigned hi = (unsigned)f2bf(acc[rf][cf][2]) | ((unsigned)f2bf(acc[rf][cf][3]) << 16);
                uint2 u; u.x = lo; u.y = hi;
                *(uint2*)(out + ((size_t)(b * 256 + n)) * 1024 + tok) = u;
            }
    }
}

// ---------------- fused masked attention (quadrant x channel-half per z) ----------------
struct PhaseCfg {
    const u16* Q; const u16* K; const u16* Vl; const u16* Vr;
    const unsigned* pl; const unsigned* pr; const unsigned char* dgp;
    float scale; float* po;
};

// r8 skeleton (best: 196us), + channel-split TLP: 2 blocks per (quad,b,i0),
// each duplicates QK+softmax (idle pipes) but computes only its 128-ch half
// of PV/output. Grid 2048 -> ~7 blocks/CU (LDS 21.8KB) vs r8's grid-capped 4.
// Per-iter: 2 barriers, counted vmcnt(16), V/masks prefetched one iter ahead.
// LDS 21760B: Ks@0 16K, Pl@16384 2560, Pr@18944 2560, rsS@21504 128, dpS@21632 128
__global__ __launch_bounds__(128, 3) void k_attn(PhaseCfg c0, PhaseCfg c1,
        PhaseCfg c2, PhaseCfg c3) {
    // XCD swizzle: all 64 blocks (32 i x 2 ch-half) of one (quad,b) on one XCD
    const int lin = blockIdx.x + 32 * blockIdx.y + 256 * blockIdx.z;
    const int xcd = lin & 7, rest = lin >> 3;          // rest in [0,256)
    const int pair = xcd * 4 + (rest >> 6);            // [0,32) = z*8+b
    const int sub = rest & 63;
    const int i0 = (sub & 31) * 32;
    const int h = sub >> 5;                            // channel half
    const int z = pair >> 3, b = pair & 7;
    const PhaseCfg c = z == 0 ? c0 : z == 1 ? c1 : z == 2 ? c2 : c3;
    const int lane = threadIdx.x & 63, w = threadIdx.x >> 6;   // 2 waves
    const int rl = lane & 15, g = lane >> 4;

    __shared__ __align__(16) char smem[21760];
    u16* Pls = (u16*)(smem + 16384);
    u16* Prs = (u16*)(smem + 18944);
    float* rsS = (float*)(smem + 21504);
    float* dpS = (float*)(smem + 21632);

    const char* Kg  = (const char*)c.K  + (size_t)b * 524288;
    const char* Vlg = (const char*)c.Vl + (size_t)b * 524288;
    const char* Vrg = (const char*)c.Vr + (size_t)b * 524288;

    // Q fragments in regs: rows i0 + w*16 + rl, k = kf*32 + g*8
    s16x8 qf[8];
    {
        const u16* Qb = c.Q + (size_t)(b * 1024 + i0 + w * 16 + rl) * 256 + g * 8;
#pragma unroll
        for (int kf = 0; kf < 8; ++kf) qf[kf] = *(const s16x8*)(Qb + kf * 32);
    }
    const int iqb = i0 + w * 16 + g * 4;
    const unsigned* lpRow = c.pl + ((size_t)(b << 10) + iqb) * 32;
    const unsigned* rpRow = c.pr + ((size_t)(b << 10) + iqb) * 32;

    unsigned dgv[4];
#pragma unroll
    for (int r = 0; r < 4; ++r)
        dgv[r] = c.dgp ? (unsigned)c.dgp[b * 1024 + iqb + r] : 0u;

    // stage K tile: 16KB, 8 gld16 per wave (128 threads)
    auto STAGE_K = [&](int j0) {
#pragma unroll
        for (int t = 0; t < 8; ++t) {
            int iid = t * 2 + w;
            int ldso = iid * 1024 + lane * 16;
            int row = ldso >> 9, inrow = ldso & 511;
            int src = inrow ^ ((row & 7) << 4);
            gld16(Kg + ((size_t)(j0 + row) * 512 + src), smem + iid * 1024);
        }
    };
    // masks for current tile, prefetched one iteration ahead (8 regs)
    unsigned lw[4], rw[4];
    auto MLOAD = [&](int jt) {
#pragma unroll
        for (int r = 0; r < 4; ++r) {
            lw[r] = lpRow[r * 32 + jt];
            rw[r] = rpRow[r * 32 + jt];
        }
    };

    STAGE_K(0);
    MLOAD(0);

    const f32x4 fz = {0.f, 0.f, 0.f, 0.f};
    f32x4 acc[2][4];
#pragma unroll
    for (int i = 0; i < 2; ++i)
#pragma unroll
        for (int j = 0; j < 4; ++j) acc[i][j] = fz;
    float mrow[4] = {-1e30f, -1e30f, -1e30f, -1e30f};
    float dden[4] = {0.f, 0.f, 0.f, 0.f};

#pragma unroll 1
    for (int jt = 0; jt < 32; ++jt) {
        const int j0 = jt * 32;

        // V fragments for this block's 128-ch half, wave's 64-ch slice
        s16x8 vl[4], vr[4];
#pragma unroll
        for (int cf = 0; cf < 4; ++cf) {
            size_t off = (size_t)(h * 128 + w * 64 + cf * 16 + rl) * 2048
                       + (size_t)(j0 + g * 8) * 2;
            vl[cf] = *(const s16x8*)(Vlg + off);
            vr[cf] = *(const s16x8*)(Vrg + off);
        }
        // in-flight: STAGE_K(jt)=8 + MLOAD(jt)=8 (issued last iter), vl/vr=8
        // drain stage+masks, keep vl/vr flying
        asm volatile("s_waitcnt vmcnt(16)" ::: "memory");
        SBAR();   // (A) K tile visible

        // S = Q K^T : 16 rows x 32 cols, all in-wave
        f32x4 s0 = fz, s1 = fz;
#pragma unroll
        for (int kk = 0; kk < 8; ++kk) {
            int jr0 = rl, jr1 = 16 + rl;
            s16x8 b0 = *(const s16x8*)(smem + jr0 * 512 + ((kk * 64 + g * 16) ^ ((jr0 & 7) << 4)));
            s16x8 b1 = *(const s16x8*)(smem + jr1 * 512 + ((kk * 64 + g * 16) ^ ((jr1 & 7) << 4)));
            s0 = mfma16(qf[kk], b0, s0);
            s1 = mfma16(qf[kk], b1, s1);
        }

        // masks from bits; cols rl (bit rl) and 16+rl (bit 16+rl)
        float sv0[4], sv1[4];
        int l0[4], l1[4], r0m[4], r1m[4];
#pragma unroll
        for (int r = 0; r < 4; ++r) {
            unsigned vw = lw[r] | rw[r];
            int row = iqb + r;
            if (jt == (row >> 5)) vw |= dgv[r] << (row & 31);
            int v0 = (vw >> rl) & 1;
            int v1 = (vw >> (16 + rl)) & 1;
            sv0[r] = v0 ? s0[r] * c.scale : -1e30f;
            sv1[r] = v1 ? s1[r] * c.scale : -1e30f;
            l0[r] = (lw[r] >> rl) & 1;        r0m[r] = (rw[r] >> rl) & 1;
            l1[r] = (lw[r] >> (16 + rl)) & 1; r1m[r] = (rw[r] >> (16 + rl)) & 1;
        }
        // full-row max in-wave (over 32 cols)
        float rsv[4];
#pragma unroll
        for (int r = 0; r < 4; ++r) {
            float t = fmaxf(sv0[r], sv1[r]);
            t = fmaxf(t, __shfl_xor(t, 1));
            t = fmaxf(t, __shfl_xor(t, 2));
            t = fmaxf(t, __shfl_xor(t, 4));
            t = fmaxf(t, __shfl_xor(t, 8));
            float mn = fmaxf(mrow[r], t);
            rsv[r] = __expf(mrow[r] - mn);
            mrow[r] = mn;
            float e0 = __expf(sv0[r] - mn);
            float e1 = __expf(sv1[r] - mn);
            dden[r] = dden[r] * rsv[r] + e0 + e1;
            int prow = w * 16 + g * 4 + r;
            Pls[prow * 40 + rl]      = l0[r]  ? f2bf(e0) : (u16)0;
            Pls[prow * 40 + 16 + rl] = l1[r]  ? f2bf(e1) : (u16)0;
            Prs[prow * 40 + rl]      = r0m[r] ? f2bf(e0) : (u16)0;
            Prs[prow * 40 + 16 + rl] = r1m[r] ? f2bf(e1) : (u16)0;
        }
        if (rl == 0) {
            f32x4 rv = {rsv[0], rsv[1], rsv[2], rsv[3]};
            *(f32x4*)(rsS + w * 16 + g * 4) = rv;
        }
        LGKM0();
        SBAR();   // (B) P + rescale visible; K reads done -> stage WAR safe

        if (jt < 31) { STAGE_K(j0 + 32); MLOAD(jt + 1); }

        // PV: this block's 128-ch half over all 32 rows; vl/vr already in regs
        f32x4 rs4[2];
#pragma unroll
        for (int rf = 0; rf < 2; ++rf) rs4[rf] = *(const f32x4*)(rsS + rf * 16 + g * 4);
#pragma unroll
        for (int rf = 0; rf < 2; ++rf)
#pragma unroll
            for (int cf = 0; cf < 4; ++cf) acc[rf][cf] *= rs4[rf];
        s16x8 pa[2], pb[2];
#pragma unroll
        for (int rf = 0; rf < 2; ++rf) {
            pa[rf] = *(const s16x8*)((char*)Pls + (rf * 16 + rl) * 80 + g * 16);
            pb[rf] = *(const s16x8*)((char*)Prs + (rf * 16 + rl) * 80 + g * 16);
        }
#pragma unroll
        for (int rf = 0; rf < 2; ++rf)
#pragma unroll
            for (int cf = 0; cf < 4; ++cf)
                acc[rf][cf] = mfma16(pb[rf], vr[cf], mfma16(pa[rf], vl[cf], acc[rf][cf]));
    }

    // denominators: reduce over rl, exchange across the 2 waves
#pragma unroll
    for (int r = 0; r < 4; ++r) {
        float d = dden[r];
        d += __shfl_xor(d, 1); d += __shfl_xor(d, 2); d += __shfl_xor(d, 4); d += __shfl_xor(d, 8);
        dden[r] = d;
    }
    if (rl == 0) {
        f32x4 dv = {dden[0], dden[1], dden[2], dden[3]};
        *(f32x4*)(dpS + w * 16 + g * 4) = dv;
    }
    __syncthreads();

#pragma unroll
    for (int rf = 0; rf < 2; ++rf) {
        f32x4 dt = *(const f32x4*)(dpS + rf * 16 + g * 4);
#pragma unroll
        for (int cf = 0; cf < 4; ++cf) {
            int col = h * 128 + w * 64 + cf * 16 + rl;
#pragma unroll
            for (int r = 0; r < 4; ++r) {
                int row = i0 + rf * 16 + g * 4 + r;
                size_t oi = (size_t)(b * 1024 + row) * 256 + col;
                float inv = dt[r] > 0.f ? 1.f / dt[r] : 0.f;
                c.po[oi] = acc[rf][cf][r] * inv;
            }
        }
    }
}

// ---------------- combine: out = relu(self + bias + (pA+pB)/max(nb,1)) ----------------
struct FinCfg {
    const float* pA; const float* pB; const float* nb;
    const u16* self; float* out;
};

__global__ __launch_bounds__(256) void k_fin(FinCfg f0, FinCfg f1, const float* bias) {
    const FinCfg f = blockIdx.y ? f1 : f0;
    int row = blockIdx.x * 4 + (threadIdx.x >> 6);
    int ch = (threadIdx.x & 63) * 4;
    size_t oi = (size_t)row * 256 + ch;
    float inv = 1.f / fmaxf(f.nb[row], 1.f);
    f32x4 a = *(const f32x4*)(f.pA + oi);
    f32x4 p = *(const f32x4*)(f.pB + oi);
    f32x4 bi = *(const f32x4*)(bias + ch);
    uint2 sv = *(const uint2*)(f.self + oi);
    float s[4] = { bf2f((u16)(sv.x & 0xffff)), bf2f((u16)(sv.x >> 16)),
                   bf2f((u16)(sv.y & 0xffff)), bf2f((u16)(sv.y >> 16)) };
    f32x4 o;
#pragma unroll
    for (int k = 0; k < 4; ++k)
        o[k] = fmaxf(s[k] + bi[k] + (a[k] + p[k]) * inv, 0.f);
    *(f32x4*)(f.out + oi) = o;
}

// ---------------- host ----------------
extern "C" void kernel_launch(void* const* d_in, const int* in_sizes, int n_in,
                              void* d_out, int out_size, void* d_ws, size_t ws_size,
                              hipStream_t stream) {
    (void)in_sizes; (void)n_in; (void)out_size; (void)ws_size;
    const float* d_node = (const float*)d_in[0];
    const float* q_node = (const float*)d_in[1];
    const float* b_self = (const float*)d_in[9];
    const int* dm = (const int*)d_in[18];
    const int* qm = (const int*)d_in[19];
    const int* ner = (const int*)d_in[20];
    const int* graph = (const int*)d_in[21];

    char* ws = (char*)d_ws;
    const size_t MB = 1024 * 1024;
    u16* xd   = (u16*)(ws + 0 * MB);
    u16* xq   = (u16*)(ws + 4 * MB);
    u16* wdm  = (u16*)(ws + 8 * MB);
    u16* wqm  = (u16*)(ws + 9 * MB);
    u16* tokd = (u16*)(ws + 10 * MB);     // [Qd, Kd, Kqd, SelfD]
    u16* tokq = (u16*)(ws + 26 * MB);     // [Qq, Kq, Kdq, SelfQ]
    u16* vtd  = (u16*)(ws + 42 * MB);     // [ddl, ddr, qdl, qdr] channel-major
    u16* vtq  = (u16*)(ws + 58 * MB);     // [qql, qqr, dql, dqr]
    float* nb_d = (float*)(ws + 74 * MB);
    float* nb_q = (float*)(ws + 74 * MB + 32768);
    unsigned char* dgd = (unsigned char*)(ws + 74 * MB + 65536);
    unsigned char* dgq = (unsigned char*)(ws + 74 * MB + 73728);
    float* Pdq  = (float*)(ws + 75 * MB);
    float* Pqd  = (float*)(ws + 83 * MB);
    unsigned* pl_dd = (unsigned*)(ws + 91 * MB);
    unsigned* pl_qq = (unsigned*)(ws + 92 * MB);
    unsigned* pl_dq = (unsigned*)(ws + 93 * MB);
    unsigned* pl_qd = (unsigned*)(ws + 94 * MB);
    unsigned* pr_dd = (unsigned*)(ws + 95 * MB);
    unsigned* pr_qq = (unsigned*)(ws + 96 * MB);
    unsigned* pr_dq = (unsigned*)(ws + 97 * MB);
    unsigned* pr_qd = (unsigned*)(ws + 98 * MB);

    float* outd = (float*)d_out;
    float* outq = outd + 2097152;

    WPtrs wp;
    wp.p[0]  = (const float*)d_in[2];   // W_dq_query -> Qd
    wp.p[1]  = (const float*)d_in[3];   // W_dk_key   -> Kd
    wp.p[2]  = (const float*)d_in[7];   // W_qd_fc    -> Kqd
    wp.p[3]  = (const float*)d_in[8];   // W_self     -> SelfD
    wp.p[4]  = (const float*)d_in[10];  // W_dd_l
    wp.p[5]  = (const float*)d_in[14];  // W_dd_r
    wp.p[6]  = (const float*)d_in[13];  // W_qd_l
    wp.p[7]  = (const float*)d_in[17];  // W_qd_r
    wp.p[8]  = (const float*)d_in[4];   // W_qq_query -> Qq
    wp.p[9]  = (const float*)d_in[5];   // W_qk_key   -> Kq
    wp.p[10] = (const float*)d_in[6];   // W_dq_fc    -> Kdq
    wp.p[11] = (const float*)d_in[8];   // W_self     -> SelfQ
    wp.p[12] = (const float*)d_in[11];  // W_qq_l
    wp.p[13] = (const float*)d_in[15];  // W_qq_r
    wp.p[14] = (const float*)d_in[12];  // W_dq_l
    wp.p[15] = (const float*)d_in[16];  // W_dq_r

    (void)hipMemsetAsync(ws + 74 * MB, 0, 65536, stream);   // nb_d + nb_q

    k_conv_w<<<1024, 256, 0, stream>>>(wp, wdm, wqm);
    k_conv_x<<<4096, 256, 0, stream>>>(d_node, q_node, xd, xq);

    QuadCfg mdd = { dm, dm, 0, 0, 1, pl_dd, pr_dd, dgd, nb_d };
    QuadCfg mqq = { qm, qm, 1024, 1024, 1, pl_qq, pr_qq, dgq, nb_q };
    QuadCfg mdq = { dm, qm, 0, 1024, 0, pl_dq, pr_dq, nullptr, nb_d };
    QuadCfg mqd = { qm, dm, 1024, 0, 0, pl_qd, pr_qd, nullptr, nb_q };
    k_mask<<<dim3(128, 8, 4), 256, 0, stream>>>(mdd, mqq, mdq, mqd, ner, graph);

    k_proj<<<dim3(64, 2, 16), 256, 0, stream>>>(xd, xq, wdm, wqm, tokd, tokq, vtd, vtq);

    const size_t M2 = 2097152;
    PhaseCfg dd = { tokd,          tokd + M2,     vtd,          vtd + M2,
                    pl_dd, pr_dd, dgd, 0.0625f, outd };
    PhaseCfg qq = { tokq,          tokq + M2,     vtq,          vtq + M2,
                    pl_qq, pr_qq, dgq, 0.0625f, outq };
    PhaseCfg dq = { xd,            tokq + 2 * M2, vtq + 2 * M2, vtq + 3 * M2,
                    pl_dq, pr_dq, nullptr, 1.0f, Pdq };
    PhaseCfg qd = { xq,            tokd + 2 * M2, vtd + 2 * M2, vtd + 3 * M2,
                    pl_qd, pr_qd, nullptr, 1.0f, Pqd };
    k_attn<<<dim3(32, 8, 8), 128, 0, stream>>>(dd, qq, dq, qd);

    FinCfg fd = { outd, Pdq, nb_d, tokd + 3 * M2, outd };
    FinCfg fq = { outq, Pqd, nb_q, tokq + 3 * M2, outq };
    k_fin<<<dim3(2048, 2), 256, 0, stream>>>(fd, fq, b_self);
}

// Round 11
// 426.024 us; speedup vs baseline: 1.1463x; 1.0371x over previous
//
#include <hip/hip_runtime.h>
#include <stdint.h>

typedef __attribute__((ext_vector_type(8))) short s16x8;
typedef __attribute__((ext_vector_type(4))) float f32x4;
typedef unsigned short u16;

#define DEV static __device__ __forceinline__

DEV f32x4 mfma16(s16x8 a, s16x8 b, f32x4 c) {
    return __builtin_amdgcn_mfma_f32_16x16x32_bf16(a, b, c, 0, 0, 0);
}

DEV void gld16(const void* g, void* l) {
    __builtin_amdgcn_global_load_lds(
        (const __attribute__((address_space(1))) void*)g,
        (__attribute__((address_space(3))) void*)l, 16, 0, 0);
}

DEV u16 f2bf(float x) {
    union { float f; unsigned u; } v; v.f = x;
    unsigned r = v.u + 0x7FFFu + ((v.u >> 16) & 1u);
    return (u16)(r >> 16);
}
DEV float bf2f(u16 h) { return __uint_as_float(((unsigned)h) << 16); }

#define SBAR() do { __builtin_amdgcn_sched_barrier(0); __builtin_amdgcn_s_barrier(); __builtin_amdgcn_sched_barrier(0); } while (0)
#define LGKM0() do { asm volatile("s_waitcnt lgkmcnt(0)" ::: "memory"); __builtin_amdgcn_sched_barrier(0); } while (0)

// ---------------- weight / input conversion ----------------
struct WPtrs { const float* p[16]; };

__global__ void k_conv_w(WPtrs wp, u16* wd, u16* wq) {
    int t = blockIdx.x * 256 + threadIdx.x;
    int mat = t >> 14;
    int e = (t & 16383) << 2;
    const float* s = wp.p[mat] + e;
    u16* d = (mat < 8 ? wd + mat * 65536 : wq + (mat - 8) * 65536) + e;
    float4 v = *(const float4*)s;
    d[0] = f2bf(v.x); d[1] = f2bf(v.y); d[2] = f2bf(v.z); d[3] = f2bf(v.w);
}

__global__ void k_conv_x(const float* dn, const float* qn, u16* xd, u16* xq) {
    int t = blockIdx.x * 256 + threadIdx.x;
    int h = t >> 19;
    int e = (t & 524287) << 2;
    const float* s = (h ? qn : dn) + e;
    u16* d = (h ? xq : xd) + e;
    float4 v = *(const float4*)s;
    d[0] = f2bf(v.x); d[1] = f2bf(v.y); d[2] = f2bf(v.z); d[3] = f2bf(v.w);
}

// ---------------- mask pre-pass: pack to bit-planes + nb rowsums ----------------
struct QuadCfg {
    const int* rm; const int* cm; int roff, coff, diag;
    unsigned* pl; unsigned* pr; unsigned char* dgp; float* nb;
};

__global__ __launch_bounds__(256) void k_mask(QuadCfg q0, QuadCfg q1, QuadCfg q2, QuadCfg q3,
        const int* ner, const int* graph) {
    const int z = blockIdx.z;
    const QuadCfg c = z == 0 ? q0 : z == 1 ? q1 : z == 2 ? q2 : q3;
    const int b = blockIdx.y;
    const int t = threadIdx.x;
    const int sub = t >> 5, w = t & 31;
    const int i = blockIdx.x * 8 + sub;
    const int rm = c.rm[b * 1024 + i] != 0;
    size_t rowbase = ((size_t)(b * 2048 + c.roff + i)) * 2048 + c.coff + w * 32;
    const int4* np = (const int4*)(ner + rowbase);
    const int4* gp = (const int4*)(graph + rowbase);
    const int4* cp = (const int4*)(c.cm + b * 1024 + w * 32);
    unsigned v = 0, gw = 0;
#pragma unroll
    for (int k = 0; k < 8; ++k) {
        int4 nv = np[k], gv = gp[k], cv = cp[k];
        unsigned bs = k * 4;
        v  |= ((unsigned)(rm & (cv.x != 0) & (nv.x != 0))) << bs;
        v  |= ((unsigned)(rm & (cv.y != 0) & (nv.y != 0))) << (bs + 1);
        v  |= ((unsigned)(rm & (cv.z != 0) & (nv.z != 0))) << (bs + 2);
        v  |= ((unsigned)(rm & (cv.w != 0) & (nv.w != 0))) << (bs + 3);
        gw |= ((unsigned)(gv.x != 0)) << bs;
        gw |= ((unsigned)(gv.y != 0)) << (bs + 1);
        gw |= ((unsigned)(gv.z != 0)) << (bs + 2);
        gw |= ((unsigned)(gv.w != 0)) << (bs + 3);
    }
    unsigned e = v;
    if (c.diag && (i >> 5) == w) {
        e &= ~(1u << (i & 31));
        c.dgp[b * 1024 + i] = (unsigned char)((v >> (i & 31)) & 1u);
    }
    unsigned lb = e & gw, rb = e & ~gw;
    size_t widx = ((size_t)(b * 1024 + i)) * 32 + w;
    c.pl[widx] = lb;
    c.pr[widx] = rb;
    int cnt = __popc(e);
    cnt += __shfl_xor(cnt, 1); cnt += __shfl_xor(cnt, 2);
    cnt += __shfl_xor(cnt, 4); cnt += __shfl_xor(cnt, 8); cnt += __shfl_xor(cnt, 16);
    if (w == 0) atomicAdd(c.nb + b * 1024 + i, (float)cnt);
}

// ---------------- projection GEMM: out = X @ W^T ----------------
__global__ __launch_bounds__(256, 1) void k_proj(const u16* xd, const u16* xq,
        const u16* wdm, const u16* wqm, u16* tokd, u16* tokq, u16* vtd, u16* vtq) {
    __shared__ __align__(16) char smem[16384];
    char* As = smem; char* Bs = smem + 8192;
    const int lane = threadIdx.x & 63, wid = threadIdx.x >> 6;
    const int z = blockIdx.z, grp = z >> 3, w = z & 7;
    const u16* X = grp ? xq : xd;
    const u16* W = (grp ? wqm : wdm) + w * 65536;
    const int m0 = blockIdx.x * 128, n0 = blockIdx.y * 128;
    const int wr = wid >> 1, wc = wid & 1;
    const int rl = lane & 15, g = lane >> 4;
    const f32x4 fz = {0.f, 0.f, 0.f, 0.f};
    f32x4 acc[4][4];
#pragma unroll
    for (int i = 0; i < 4; ++i)
#pragma unroll
        for (int j = 0; j < 4; ++j) acc[i][j] = fz;

    for (int kt = 0; kt < 8; ++kt) {
#pragma unroll
        for (int t = 0; t < 2; ++t) {
            int iid = wid * 2 + t;
            int ldso = iid * 1024 + lane * 16;
            int row = ldso >> 6, inrow = ldso & 63;
            int src = inrow ^ ((row & 3) << 4);
            gld16((const char*)X + ((size_t)(m0 + row) * 512 + kt * 64 + src), As + iid * 1024);
            gld16((const char*)W + ((size_t)(n0 + row) * 512 + kt * 64 + src), Bs + iid * 1024);
        }
        __syncthreads();
        s16x8 av[4], bv[4];
#pragma unroll
        for (int rf = 0; rf < 4; ++rf) {
            int row = wr * 64 + rf * 16 + rl;
            av[rf] = *(const s16x8*)(As + row * 64 + ((g * 16) ^ ((row & 3) << 4)));
        }
#pragma unroll
        for (int cf = 0; cf < 4; ++cf) {
            int row = wc * 64 + cf * 16 + rl;
            bv[cf] = *(const s16x8*)(Bs + row * 64 + ((g * 16) ^ ((row & 3) << 4)));
        }
#pragma unroll
        for (int rf = 0; rf < 4; ++rf)
#pragma unroll
            for (int cf = 0; cf < 4; ++cf)
                acc[rf][cf] = mfma16(av[rf], bv[cf], acc[rf][cf]);
        __syncthreads();
    }
    if (w < 4) {
        u16* out = (grp ? tokq : tokd) + (size_t)w * 2097152;
#pragma unroll
        for (int rf = 0; rf < 4; ++rf)
#pragma unroll
            for (int cf = 0; cf < 4; ++cf) {
                int n = n0 + wc * 64 + cf * 16 + rl;
                int m = m0 + wr * 64 + rf * 16 + g * 4;
#pragma unroll
                for (int r = 0; r < 4; ++r)
                    out[(size_t)(m + r) * 256 + n] = f2bf(acc[rf][cf][r]);
            }
    } else {
        u16* out = (grp ? vtq : vtd) + (size_t)(w - 4) * 2097152;
#pragma unroll
        for (int rf = 0; rf < 4; ++rf)
#pragma unroll
            for (int cf = 0; cf < 4; ++cf) {
                int n = n0 + wc * 64 + cf * 16 + rl;
                int m = m0 + wr * 64 + rf * 16 + g * 4;
                int b = m >> 10, tok = m & 1023;
                unsigned lo = (unsigned)f2bf(acc[rf][cf][0]) | ((unsigned)f2bf(acc[rf][cf][1]) << 16);
                unsigned hi = (unsigned)f2bf(acc[rf][cf][2]) | ((unsigned)f2bf(acc[rf][cf][3]) << 16);
                uint2 u; u.x = lo; u.y = hi;
                *(uint2*)(out + ((size_t)(b * 256 + n)) * 1024 + tok) = u;
            }
    }
}

// ---------------- fused masked attention (one quadrant per z) ----------------
struct PhaseCfg {
    const u16* Q; const u16* K; const u16* Vl; const u16* Vr;
    const unsigned* pl; const unsigned* pr; const unsigned char* dgp;
    float scale; float* po;
};

// r8 skeleton scaled 2x2: BM=64, TILE_J=64, 16 iterations, 4 waves.
// Wave w owns rows w*16..+16: QK (64 cols) + FULL-ROW softmax in-wave
// (denominator complete in-wave); PV: wave's 64-ch slice over all 64 rows.
// 2 barriers/iter. P bounced via XOR-swizzled [64][128B] LDS (K's proven
// swizzle family). V in 2 k-chunks: c0 at top (vmcnt(8) drains only
// stage+masks), c1 during softmax -> PV auto-waits never drain the
// in-flight next-tile stage (in-order queue: [Vc0][Vc1][STAGE][mask]).
// LDS 49664B: Ks@0 32K, Pl@32768 8K, Pr@40960 8K, rsS@49152 256, dpS@49408 256
__global__ __launch_bounds__(256, 2) void k_attn(PhaseCfg c0, PhaseCfg c1,
        PhaseCfg c2, PhaseCfg c3) {
    // XCD swizzle: the 16 i-blocks of each of 4 (quad,b) pairs per XCD
    const int lin = blockIdx.x + 16 * blockIdx.y + 128 * blockIdx.z;
    const int xcd = lin & 7, rest = lin >> 3;          // rest in [0,64)
    const int pair = xcd * 4 + (rest >> 4);            // [0,32) = z*8+b
    const int i0 = (rest & 15) * 64;
    const int z = pair >> 3, b = pair & 7;
    const PhaseCfg c = z == 0 ? c0 : z == 1 ? c1 : z == 2 ? c2 : c3;
    const int lane = threadIdx.x & 63, w = threadIdx.x >> 6;   // 4 waves
    const int rl = lane & 15, g = lane >> 4;

    __shared__ __align__(16) char smem[49664];
    char* Pls = smem + 32768;      // [64][128B], swz ^((row&7)<<4)
    char* Prs = smem + 40960;
    float* rsS = (float*)(smem + 49152);
    float* dpS = (float*)(smem + 49408);

    const char* Kg  = (const char*)c.K  + (size_t)b * 524288;
    const char* Vlg = (const char*)c.Vl + (size_t)b * 524288;
    const char* Vrg = (const char*)c.Vr + (size_t)b * 524288;

    // Q fragments: wave's 16 rows (i0 + w*16 + rl), k = kf*32 + g*8
    s16x8 qf[8];
    {
        const u16* Qb = c.Q + (size_t)(b * 1024 + i0 + w * 16 + rl) * 256 + g * 8;
#pragma unroll
        for (int kf = 0; kf < 8; ++kf) qf[kf] = *(const s16x8*)(Qb + kf * 32);
    }
    const int iqb = i0 + w * 16 + g * 4;
    const unsigned* lpRow = c.pl + ((size_t)(b << 10) + iqb) * 32;
    const unsigned* rpRow = c.pr + ((size_t)(b << 10) + iqb) * 32;

    unsigned dgv[4];
#pragma unroll
    for (int r = 0; r < 4; ++r)
        dgv[r] = c.dgp ? (unsigned)c.dgp[b * 1024 + iqb + r] : 0u;

    // stage K tile: 32KB (64 rows x 512B), 8 gld16 per wave (256 threads)
    auto STAGE_K = [&](int j0) {
#pragma unroll
        for (int t = 0; t < 8; ++t) {
            int iid = t * 4 + w;
            int ldso = iid * 1024 + lane * 16;
            int row = ldso >> 9, inrow = ldso & 511;
            int src = inrow ^ ((row & 7) << 4);
            gld16(Kg + ((size_t)(j0 + row) * 512 + src), smem + iid * 1024);
        }
    };
    // masks: 2 words per row (64 cols), prefetched one iteration ahead
    unsigned lwA[4], lwB[4], rwA[4], rwB[4];
    auto MLOAD = [&](int jt) {
#pragma unroll
        for (int r = 0; r < 4; ++r) {
            uint2 lv = *(const uint2*)(lpRow + r * 32 + jt * 2);
            uint2 rv = *(const uint2*)(rpRow + r * 32 + jt * 2);
            lwA[r] = lv.x; lwB[r] = lv.y; rwA[r] = rv.x; rwB[r] = rv.y;
        }
    };

    STAGE_K(0);
    MLOAD(0);

    const f32x4 fz = {0.f, 0.f, 0.f, 0.f};
    f32x4 acc[4][4];                 // [row frag 0..3][ch frag 0..3]
#pragma unroll
    for (int i = 0; i < 4; ++i)
#pragma unroll
        for (int j = 0; j < 4; ++j) acc[i][j] = fz;
    float mrow[4] = {-1e30f, -1e30f, -1e30f, -1e30f};
    float dden[4] = {0.f, 0.f, 0.f, 0.f};

#pragma unroll 1
    for (int jt = 0; jt < 16; ++jt) {
        const int j0 = jt * 64;

        // V chunk 0 (k = j0..j0+32): wave's 64-ch slice
        s16x8 vl0[4], vr0[4];
#pragma unroll
        for (int cf = 0; cf < 4; ++cf) {
            size_t off = (size_t)(w * 64 + cf * 16 + rl) * 2048 + (size_t)(j0 + g * 8) * 2;
            vl0[cf] = *(const s16x8*)(Vlg + off);
            vr0[cf] = *(const s16x8*)(Vrg + off);
        }
        // queue: [STAGE8][mask4] (prev iter) then [Vc0 8] -> drain stage+mask
        asm volatile("s_waitcnt vmcnt(8)" ::: "memory");
        SBAR();   // (A) K tile visible

        // S = Q K^T : 16 rows x 64 cols, in-wave
        f32x4 s[4] = {fz, fz, fz, fz};
#pragma unroll
        for (int kk = 0; kk < 8; ++kk) {
#pragma unroll
            for (int cg = 0; cg < 4; ++cg) {
                int jr = cg * 16 + rl;
                s16x8 bv = *(const s16x8*)(smem + jr * 512 + ((kk * 64 + g * 16) ^ ((jr & 7) << 4)));
                s[cg] = mfma16(qf[kk], bv, s[cg]);
            }
        }

        // masks + full-row online softmax (64 cols in-wave)
        float ev[4][4];   // [r][cg]
        int lb[4][4], rb[4][4];
        float rsv[4];
#pragma unroll
        for (int r = 0; r < 4; ++r) {
            int row = iqb + r;
            unsigned vwA = lwA[r] | rwA[r];
            unsigned vwB = lwB[r] | rwB[r];
            if ((row >> 5) == jt * 2)     vwA |= dgv[r] << (row & 31);
            if ((row >> 5) == jt * 2 + 1) vwB |= dgv[r] << (row & 31);
            int v0 = (vwA >> rl) & 1, v1 = (vwA >> (16 + rl)) & 1;
            int v2 = (vwB >> rl) & 1, v3 = (vwB >> (16 + rl)) & 1;
            float sv0 = v0 ? s[0][r] * c.scale : -1e30f;
            float sv1 = v1 ? s[1][r] * c.scale : -1e30f;
            float sv2 = v2 ? s[2][r] * c.scale : -1e30f;
            float sv3 = v3 ? s[3][r] * c.scale : -1e30f;
            lb[r][0] = (lwA[r] >> rl) & 1;        rb[r][0] = (rwA[r] >> rl) & 1;
            lb[r][1] = (lwA[r] >> (16 + rl)) & 1; rb[r][1] = (rwA[r] >> (16 + rl)) & 1;
            lb[r][2] = (lwB[r] >> rl) & 1;        rb[r][2] = (rwB[r] >> rl) & 1;
            lb[r][3] = (lwB[r] >> (16 + rl)) & 1; rb[r][3] = (rwB[r] >> (16 + rl)) & 1;
            float t = fmaxf(fmaxf(sv0, sv1), fmaxf(sv2, sv3));
            t = fmaxf(t, __shfl_xor(t, 1));
            t = fmaxf(t, __shfl_xor(t, 2));
            t = fmaxf(t, __shfl_xor(t, 4));
            t = fmaxf(t, __shfl_xor(t, 8));
            float mn = fmaxf(mrow[r], t);
            rsv[r] = __expf(mrow[r] - mn);
            mrow[r] = mn;
            ev[r][0] = __expf(sv0 - mn);
            ev[r][1] = __expf(sv1 - mn);
            ev[r][2] = __expf(sv2 - mn);
            ev[r][3] = __expf(sv3 - mn);
            dden[r] = dden[r] * rsv[r] + ev[r][0] + ev[r][1] + ev[r][2] + ev[r][3];
            int prow = w * 16 + g * 4 + r;
            int sw = (prow & 7) << 4;
#pragma unroll
            for (int cg = 0; cg < 4; ++cg) {
                int off = prow * 128 + ((cg * 32 + rl * 2) ^ sw);
                *(u16*)(Pls + off) = lb[r][cg] ? f2bf(ev[r][cg]) : (u16)0;
                *(u16*)(Prs + off) = rb[r][cg] ? f2bf(ev[r][cg]) : (u16)0;
            }
        }
        // V chunk 1 issued here: slack until PV chunk 1
        s16x8 vl1[4], vr1[4];
#pragma unroll
        for (int cf = 0; cf < 4; ++cf) {
            size_t off = (size_t)(w * 64 + cf * 16 + rl) * 2048 + (size_t)(j0 + 32 + g * 8) * 2;
            vl1[cf] = *(const s16x8*)(Vlg + off);
            vr1[cf] = *(const s16x8*)(Vrg + off);
        }
        if (rl == 0) {
            f32x4 rv = {rsv[0], rsv[1], rsv[2], rsv[3]};
            *(f32x4*)(rsS + w * 16 + g * 4) = rv;
        }
        LGKM0();
        SBAR();   // (B) P + rescale visible; K reads done -> stage WAR safe

        if (jt < 15) { STAGE_K(j0 + 64); MLOAD(jt + 1); }

        // PV: wave's 64-ch slice over all 64 rows, k=64 in 2 chunks
        f32x4 rs4[4];
#pragma unroll
        for (int rf = 0; rf < 4; ++rf) rs4[rf] = *(const f32x4*)(rsS + rf * 16 + g * 4);
#pragma unroll
        for (int rf = 0; rf < 4; ++rf)
#pragma unroll
            for (int cf = 0; cf < 4; ++cf) acc[rf][cf] *= rs4[rf];
#pragma unroll
        for (int rf = 0; rf < 4; ++rf) {
            int row = rf * 16 + rl;
            int off0 = row * 128 + ((g * 16) ^ ((row & 7) << 4));
            s16x8 pa = *(const s16x8*)(Pls + off0);
            s16x8 pb = *(const s16x8*)(Prs + off0);
#pragma unroll
            for (int cf = 0; cf < 4; ++cf)
                acc[rf][cf] = mfma16(pb, vr0[cf], mfma16(pa, vl0[cf], acc[rf][cf]));
        }
#pragma unroll
        for (int rf = 0; rf < 4; ++rf) {
            int row = rf * 16 + rl;
            int off1 = row * 128 + ((64 + g * 16) ^ ((row & 7) << 4));
            s16x8 pa = *(const s16x8*)(Pls + off1);
            s16x8 pb = *(const s16x8*)(Prs + off1);
#pragma unroll
            for (int cf = 0; cf < 4; ++cf)
                acc[rf][cf] = mfma16(pb, vr1[cf], mfma16(pa, vl1[cf], acc[rf][cf]));
        }
    }

    // denominators are complete in-wave: reduce over rl, publish all 64 rows
#pragma unroll
    for (int r = 0; r < 4; ++r) {
        float d = dden[r];
        d += __shfl_xor(d, 1); d += __shfl_xor(d, 2); d += __shfl_xor(d, 4); d += __shfl_xor(d, 8);
        dden[r] = d;
    }
    if (rl == 0) {
        f32x4 dv = {dden[0], dden[1], dden[2], dden[3]};
        *(f32x4*)(dpS + w * 16 + g * 4) = dv;
    }
    __syncthreads();

#pragma unroll
    for (int rf = 0; rf < 4; ++rf) {
        f32x4 dt = *(const f32x4*)(dpS + rf * 16 + g * 4);
#pragma unroll
        for (int cf = 0; cf < 4; ++cf) {
            int col = w * 64 + cf * 16 + rl;
#pragma unroll
            for (int r = 0; r < 4; ++r) {
                int row = i0 + rf * 16 + g * 4 + r;
                size_t oi = (size_t)(b * 1024 + row) * 256 + col;
                float inv = dt[r] > 0.f ? 1.f / dt[r] : 0.f;
                c.po[oi] = acc[rf][cf][r] * inv;
            }
        }
    }
}

// ---------------- combine: out = relu(self + bias + (pA+pB)/max(nb,1)) ----------------
struct FinCfg {
    const float* pA; const float* pB; const float* nb;
    const u16* self; float* out;
};

__global__ __launch_bounds__(256) void k_fin(FinCfg f0, FinCfg f1, const float* bias) {
    const FinCfg f = blockIdx.y ? f1 : f0;
    int row = blockIdx.x * 4 + (threadIdx.x >> 6);
    int ch = (threadIdx.x & 63) * 4;
    size_t oi = (size_t)row * 256 + ch;
    float inv = 1.f / fmaxf(f.nb[row], 1.f);
    f32x4 a = *(const f32x4*)(f.pA + oi);
    f32x4 p = *(const f32x4*)(f.pB + oi);
    f32x4 bi = *(const f32x4*)(bias + ch);
    uint2 sv = *(const uint2*)(f.self + oi);
    float s[4] = { bf2f((u16)(sv.x & 0xffff)), bf2f((u16)(sv.x >> 16)),
                   bf2f((u16)(sv.y & 0xffff)), bf2f((u16)(sv.y >> 16)) };
    f32x4 o;
#pragma unroll
    for (int k = 0; k < 4; ++k)
        o[k] = fmaxf(s[k] + bi[k] + (a[k] + p[k]) * inv, 0.f);
    *(f32x4*)(f.out + oi) = o;
}

// ---------------- host ----------------
extern "C" void kernel_launch(void* const* d_in, const int* in_sizes, int n_in,
                              void* d_out, int out_size, void* d_ws, size_t ws_size,
                              hipStream_t stream) {
    (void)in_sizes; (void)n_in; (void)out_size; (void)ws_size;
    const float* d_node = (const float*)d_in[0];
    const float* q_node = (const float*)d_in[1];
    const float* b_self = (const float*)d_in[9];
    const int* dm = (const int*)d_in[18];
    const int* qm = (const int*)d_in[19];
    const int* ner = (const int*)d_in[20];
    const int* graph = (const int*)d_in[21];

    char* ws = (char*)d_ws;
    const size_t MB = 1024 * 1024;
    u16* xd   = (u16*)(ws + 0 * MB);
    u16* xq   = (u16*)(ws + 4 * MB);
    u16* wdm  = (u16*)(ws + 8 * MB);
    u16* wqm  = (u16*)(ws + 9 * MB);
    u16* tokd = (u16*)(ws + 10 * MB);     // [Qd, Kd, Kqd, SelfD]
    u16* tokq = (u16*)(ws + 26 * MB);     // [Qq, Kq, Kdq, SelfQ]
    u16* vtd  = (u16*)(ws + 42 * MB);     // [ddl, ddr, qdl, qdr] channel-major
    u16* vtq  = (u16*)(ws + 58 * MB);     // [qql, qqr, dql, dqr]
    float* nb_d = (float*)(ws + 74 * MB);
    float* nb_q = (float*)(ws + 74 * MB + 32768);
    unsigned char* dgd = (unsigned char*)(ws + 74 * MB + 65536);
    unsigned char* dgq = (unsigned char*)(ws + 74 * MB + 73728);
    float* Pdq  = (float*)(ws + 75 * MB);
    float* Pqd  = (float*)(ws + 83 * MB);
    unsigned* pl_dd = (unsigned*)(ws + 91 * MB);
    unsigned* pl_qq = (unsigned*)(ws + 92 * MB);
    unsigned* pl_dq = (unsigned*)(ws + 93 * MB);
    unsigned* pl_qd = (unsigned*)(ws + 94 * MB);
    unsigned* pr_dd = (unsigned*)(ws + 95 * MB);
    unsigned* pr_qq = (unsigned*)(ws + 96 * MB);
    unsigned* pr_dq = (unsigned*)(ws + 97 * MB);
    unsigned* pr_qd = (unsigned*)(ws + 98 * MB);

    float* outd = (float*)d_out;
    float* outq = outd + 2097152;

    WPtrs wp;
    wp.p[0]  = (const float*)d_in[2];   // W_dq_query -> Qd
    wp.p[1]  = (const float*)d_in[3];   // W_dk_key   -> Kd
    wp.p[2]  = (const float*)d_in[7];   // W_qd_fc    -> Kqd
    wp.p[3]  = (const float*)d_in[8];   // W_self     -> SelfD
    wp.p[4]  = (const float*)d_in[10];  // W_dd_l
    wp.p[5]  = (const float*)d_in[14];  // W_dd_r
    wp.p[6]  = (const float*)d_in[13];  // W_qd_l
    wp.p[7]  = (const float*)d_in[17];  // W_qd_r
    wp.p[8]  = (const float*)d_in[4];   // W_qq_query -> Qq
    wp.p[9]  = (const float*)d_in[5];   // W_qk_key   -> Kq
    wp.p[10] = (const float*)d_in[6];   // W_dq_fc    -> Kdq
    wp.p[11] = (const float*)d_in[8];   // W_self     -> SelfQ
    wp.p[12] = (const float*)d_in[11];  // W_qq_l
    wp.p[13] = (const float*)d_in[15];  // W_qq_r
    wp.p[14] = (const float*)d_in[12];  // W_dq_l
    wp.p[15] = (const float*)d_in[16];  // W_dq_r

    (void)hipMemsetAsync(ws + 74 * MB, 0, 65536, stream);   // nb_d + nb_q

    k_conv_w<<<1024, 256, 0, stream>>>(wp, wdm, wqm);
    k_conv_x<<<4096, 256, 0, stream>>>(d_node, q_node, xd, xq);

    QuadCfg mdd = { dm, dm, 0, 0, 1, pl_dd, pr_dd, dgd, nb_d };
    QuadCfg mqq = { qm, qm, 1024, 1024, 1, pl_qq, pr_qq, dgq, nb_q };
    QuadCfg mdq = { dm, qm, 0, 1024, 0, pl_dq, pr_dq, nullptr, nb_d };
    QuadCfg mqd = { qm, dm, 1024, 0, 0, pl_qd, pr_qd, nullptr, nb_q };
    k_mask<<<dim3(128, 8, 4), 256, 0, stream>>>(mdd, mqq, mdq, mqd, ner, graph);

    k_proj<<<dim3(64, 2, 16), 256, 0, stream>>>(xd, xq, wdm, wqm, tokd, tokq, vtd, vtq);

    const size_t M2 = 2097152;
    PhaseCfg dd = { tokd,          tokd + M2,     vtd,          vtd + M2,
                    pl_dd, pr_dd, dgd, 0.0625f, outd };
    PhaseCfg qq = { tokq,          tokq + M2,     vtq,          vtq + M2,
                    pl_qq, pr_qq, dgq, 0.0625f, outq };
    PhaseCfg dq = { xd,            tokq + 2 * M2, vtq + 2 * M2, vtq + 3 * M2,
                    pl_dq, pr_dq, nullptr, 1.0f, Pdq };
    PhaseCfg qd = { xq,            tokd + 2 * M2, vtd + 2 * M2, vtd + 3 * M2,
                    pl_qd, pr_qd, nullptr, 1.0f, Pqd };
    k_attn<<<dim3(16, 8, 4), 256, 0, stream>>>(dd, qq, dq, qd);

    FinCfg fd = { outd, Pdq, nb_d, tokd + 3 * M2, outd };
    FinCfg fq = { outq, Pqd, nb_q, tokq + 3 * M2, outq };
    k_fin<<<dim3(2048, 2), 256, 0, stream>>>(fd, fq, b_self);
}